// Round 3
// baseline (621.506 us; speedup 1.0000x reference)
//
#include <hip/hip_runtime.h>

typedef unsigned short ushort_t;
typedef unsigned int uint_t;

#define DD 256
#define HH 512
#define BB 128

__device__ __forceinline__ float bf2f(ushort_t u) {
    union { uint_t i; float f; } t;
    t.i = ((uint_t)u) << 16;
    return t.f;
}

__device__ __forceinline__ ushort_t f2bf(float f) {
    union { float f; uint_t i; } t;
    t.f = f;
    uint_t x = t.i;
    return (ushort_t)((x + 0x7fffu + ((x >> 16) & 1u)) >> 16);
}

__device__ __forceinline__ float elu_f(float x) {
    return x > 0.f ? x : expm1f(x);
}

// load input element idx as f32, honoring runtime dtype flag (1 = bf16, 0 = f32)
__device__ __forceinline__ float ldin(const void* p, int idx, int bf) {
    return bf ? bf2f(((const ushort_t*)p)[idx]) : ((const float*)p)[idx];
}

// ---- dtype detector: x ~ N(0,1). If packed bf16, low halfword's bits 7..14
// are a real bf16 exponent (~[107,129]); if f32, they are mantissa noise
// (~16% in range). Count over 8192 dwords (32KB, in-bounds either way). ----
__global__ void detect_dtype(const uint_t* __restrict__ xw, int* __restrict__ flag) {
    __shared__ int cnt;
    if (threadIdx.x == 0) cnt = 0;
    __syncthreads();
    int local = 0;
    for (int k = threadIdx.x; k < 8192; k += 256) {
        uint_t e = (xw[k] >> 7) & 0xFFu;
        local += (e >= 100u && e <= 140u) ? 1 : 0;
    }
    atomicAdd(&cnt, local);
    __syncthreads();
    if (threadIdx.x == 0) *flag = (cnt > 4096) ? 1 : 0;
}

// ---- prep: W0 [H,D] -> W0P[i*H+h] = float2(mu_W0[h,i], lv_W0[h,i]) ----
__global__ void prep_w0(const void* __restrict__ w0m, const void* __restrict__ w0l,
                        const int* __restrict__ flag, float2* __restrict__ out) {
    int t = blockIdx.x * 256 + threadIdx.x;   // t = i*512 + h
    int h = t & (HH - 1), i = t >> 9;
    int bf = *flag;
    int idx = h * DD + i;
    out[t] = make_float2(ldin(w0m, idx, bf), ldin(w0l, idx, bf));
}

// ---- prep: W1 [H,H] -> pre-masked W1P[hp*H+h] = m1[h,hp]*float2(W1m[h,hp],W1l[h,hp]) ----
__global__ void prep_w1(const void* __restrict__ w1m, const void* __restrict__ w1l,
                        const int* __restrict__ flag, float2* __restrict__ out) {
    int t = blockIdx.x * 256 + threadIdx.x;   // t = hp*512 + h
    int h = t & (HH - 1), hp = t >> 9;
    int bf = *flag;
    float2 v = make_float2(0.f, 0.f);
    if ((h % 255) >= (hp % 255)) {            // dh_h >= dh_hp, dh = (h%255)+1
        int idx = h * HH + hp;
        v = make_float2(ldin(w1m, idx, bf), ldin(w1l, idx, bf));
    }
    out[t] = v;
}

// ---- prep: Wo [D,H] -> WoP[i*H+h] = float2(mu_Wo[i,h], lv_Wo[i,h]) ----
__global__ void prep_wo(const void* __restrict__ wom, const void* __restrict__ wol,
                        const int* __restrict__ flag, float2* __restrict__ out) {
    int t = blockIdx.x * 256 + threadIdx.x;   // t = i*512 + h
    int bf = *flag;
    out[t] = make_float2(ldin(wom, t, bf), ldin(wol, t, bf));
}

// ---- main: one wave per batch row; incremental autoregressive evaluation ----
__global__ __launch_bounds__(64) void made_main(
    const void* __restrict__ x,
    const void* __restrict__ mu_b0, const void* __restrict__ mu_b1,
    const void* __restrict__ mu_bo,
    const void* __restrict__ lv_b0, const void* __restrict__ lv_b1,
    const void* __restrict__ lv_bo,
    const float2* __restrict__ W0P, const float2* __restrict__ W1P,
    const float2* __restrict__ WoP,
    const int* __restrict__ flagp, void* __restrict__ out)
{
    __shared__ float2 h1_s[HH];     // (mu h1, lv h1); 0 until finalized
    __shared__ float  x_s[DD];
    __shared__ float2 bo_s[DD];
    __shared__ float2 st[4];        // h0 staging for this step's finalizers

    const int lane = threadIdx.x;   // 0..63
    const int row  = blockIdx.x;    // 0..127
    const int bf   = *flagp;

    float a0m[8], a0l[8], a1m[8], a1l[8];
    int fin_i[8];
    #pragma unroll
    for (int e = 0; e < 8; ++e) {
        int h = lane + 64 * e;
        a0m[e] = ldin(mu_b0, h, bf);
        a0l[e] = ldin(lv_b0, h, bf);
        a1m[e] = ldin(mu_b1, h, bf);
        a1l[e] = ldin(lv_b1, h, bf);
        h1_s[h] = make_float2(0.f, 0.f);
        fin_i[e] = h % 255;          // finalize at step i = dh-1
    }
    #pragma unroll
    for (int e = 0; e < 4; ++e) {
        int j = lane + 64 * e;
        x_s[j]  = ldin(x, row * DD + j, bf);
        bo_s[j] = make_float2(ldin(mu_bo, j, bf), ldin(lv_bo, j, bf));
    }
    __syncthreads();

    ushort_t* yb = (ushort_t*)out;
    float*    yf = (float*)out;
    float ls_sum = 0.f;

    for (int i = 0; i < DD; ++i) {
        // ---- output column i (mask mo implicit: h1_s == 0 for un-finalized) ----
        float accm = 0.f, accl = 0.f;
        #pragma unroll
        for (int e = 0; e < 8; ++e) {
            int h = lane + 64 * e;
            float2 wo = WoP[i * HH + h];
            float2 h1 = h1_s[h];
            accm += wo.x * h1.x;
            accl += wo.y * h1.y;
        }
        #pragma unroll
        for (int o = 32; o > 0; o >>= 1) {
            accm += __shfl_xor(accm, o, 64);
            accl += __shfl_xor(accl, o, 64);
        }
        float mu = accm + bo_s[i].x;
        float ls = 0.5f * (accl + bo_s[i].y);
        ls_sum += ls;
        float v = (x_s[i] - mu) / (expf(ls) + 1e-12f);
        if (lane == 0) {
            if (bf) yb[row * DD + i] = f2bf(v);
            else    yf[row * DD + i] = v;
        }

        // ---- a0 += v * W0[:,i] (finalized units' a0 is dead; mask not needed) ----
        #pragma unroll
        for (int e = 0; e < 8; ++e) {
            int h = lane + 64 * e;
            float2 w0 = W0P[i * HH + h];
            a0m[e] += v * w0.x;
            a0l[e] += v * w0.y;
        }

        // ---- stage h0 = elu(a0) for units finalizing this step ----
        __syncthreads();
        #pragma unroll
        for (int e = 0; e < 8; ++e) {
            if (fin_i[e] == i) {
                int h = lane + 64 * e;
                int slot = (h >= 510) ? 2 : (h >= 255 ? 1 : 0);
                st[slot] = make_float2(elu_f(a0m[e]), elu_f(a0l[e]));
            }
        }
        __syncthreads();

        // ---- push finalizers' h0 into a1 (W1P pre-masked with m1) ----
        int nf = (i <= 1) ? 3 : (i <= 254 ? 2 : 0);
        for (int t = 0; t < nf; ++t) {
            int hp = (t == 0) ? i : (t == 1 ? i + 255 : 510 + i);
            float2 h0 = st[t];
            #pragma unroll
            for (int e = 0; e < 8; ++e) {
                int h = lane + 64 * e;
                float2 w1 = W1P[hp * HH + h];
                a1m[e] += w1.x * h0.x;
                a1l[e] += w1.y * h0.y;
            }
        }

        // ---- h1 = elu(a1) for the same finalizers (their a1 is now complete) ----
        #pragma unroll
        for (int e = 0; e < 8; ++e) {
            if (fin_i[e] == i) {
                int h = lane + 64 * e;
                h1_s[h] = make_float2(elu_f(a1m[e]), elu_f(a1l[e]));
            }
        }
        __syncthreads();
    }

    if (lane == 0) {
        if (bf) yb[BB * DD + row] = f2bf(ls_sum);
        else    yf[BB * DD + row] = ls_sum;
    }
}

extern "C" void kernel_launch(void* const* d_in, const int* in_sizes, int n_in,
                              void* d_out, int out_size, void* d_ws, size_t ws_size,
                              hipStream_t stream) {
    const void* x     = d_in[0];
    const void* mu_W0 = d_in[1];
    const void* mu_b0 = d_in[2];
    const void* mu_W1 = d_in[3];
    const void* mu_b1 = d_in[4];
    const void* mu_Wo = d_in[5];
    const void* mu_bo = d_in[6];
    const void* lv_W0 = d_in[7];
    const void* lv_b0 = d_in[8];
    const void* lv_W1 = d_in[9];
    const void* lv_b1 = d_in[10];
    const void* lv_Wo = d_in[11];
    const void* lv_bo = d_in[12];

    char* ws = (char*)d_ws;
    float2* W0P = (float2*)(ws);                       // 256*512*8 = 1 MiB
    float2* W1P = (float2*)(ws + (1u << 20));          // 512*512*8 = 2 MiB
    float2* WoP = (float2*)(ws + (3u << 20));          // 1 MiB
    int*    flag = (int*)(ws + (4u << 20));            // 4 B

    detect_dtype<<<1, 256, 0, stream>>>((const uint_t*)x, flag);
    prep_w0<<<(DD * HH) / 256, 256, 0, stream>>>(mu_W0, lv_W0, flag, W0P);
    prep_w1<<<(HH * HH) / 256, 256, 0, stream>>>(mu_W1, lv_W1, flag, W1P);
    prep_wo<<<(DD * HH) / 256, 256, 0, stream>>>(mu_Wo, lv_Wo, flag, WoP);
    made_main<<<BB, 64, 0, stream>>>(x, mu_b0, mu_b1, mu_bo,
                                     lv_b0, lv_b1, lv_bo,
                                     W0P, W1P, WoP, flag, d_out);
}

// Round 4
// 316.839 us; speedup vs baseline: 1.9616x; 1.9616x over previous
//
#include <hip/hip_runtime.h>

#define DD 256
#define HH 512
#define BB 128

__device__ __forceinline__ float elu_f(float x) {
    return x > 0.f ? x : (__expf(x) - 1.f);
}

__device__ __forceinline__ float bcast(float v, int l) {
    return __uint_as_float(__builtin_amdgcn_readlane(__float_as_uint(v), (unsigned)l));
}

__device__ __forceinline__ float sel8(const float (&a)[8], int e) {
    float v = a[0];
    #pragma unroll
    for (int k = 1; k < 8; ++k) v = (e == k) ? a[k] : v;
    return v;
}

// load one 512-wide row pair (m-array, l-array) into 4 float4s:
// buf[0]=m[h=4*lane..+3], buf[1]=m[256+4*lane..+3], buf[2]/buf[3] same for l
__device__ __forceinline__ void loadr(float4 (&buf)[4], const float* pm, const float* pl,
                                      int r, int lane) {
    const float4* a = (const float4*)(pm + r * HH);
    const float4* b = (const float4*)(pl + r * HH);
    buf[0] = a[lane];
    buf[1] = a[64 + lane];
    buf[2] = b[lane];
    buf[3] = b[64 + lane];
}

__device__ __forceinline__ float dot8(const float4& w0, const float4& w1, const float (&h)[8]) {
    return w0.x*h[0] + w0.y*h[1] + w0.z*h[2] + w0.w*h[3]
         + w1.x*h[4] + w1.y*h[5] + w1.z*h[6] + w1.w*h[7];
}

__device__ __forceinline__ void axpy8(float (&a)[8], const float4& w0, const float4& w1, float v) {
    a[0] += v*w0.x; a[1] += v*w0.y; a[2] += v*w0.z; a[3] += v*w0.w;
    a[4] += v*w1.x; a[5] += v*w1.y; a[6] += v*w1.z; a[7] += v*w1.w;
}

__device__ __forceinline__ void push2(float (&a)[8], const float4& wA0, const float4& wA1,
                                      const float4& wB0, const float4& wB1, float p0, float p1) {
    a[0] += wA0.x*p0 + wB0.x*p1; a[1] += wA0.y*p0 + wB0.y*p1;
    a[2] += wA0.z*p0 + wB0.z*p1; a[3] += wA0.w*p0 + wB0.w*p1;
    a[4] += wA1.x*p0 + wB1.x*p1; a[5] += wA1.y*p0 + wB1.y*p1;
    a[6] += wA1.z*p0 + wB1.z*p1; a[7] += wA1.w*p0 + wB1.w*p1;
}

__device__ __forceinline__ void push1(float (&a)[8], const float4& w0, const float4& w1, float p) {
    a[0] += w0.x*p; a[1] += w0.y*p; a[2] += w0.z*p; a[3] += w0.w*p;
    a[4] += w1.x*p; a[5] += w1.y*p; a[6] += w1.z*p; a[7] += w1.w*p;
}

// ---- fused prep: W1T[hp*512+h] = m1(h,hp)*W1[h,hp]; W0T[i*512+h] = W0[h,i] ----
__global__ void prep(const float* __restrict__ w0m_, const float* __restrict__ w0l_,
                     const float* __restrict__ w1m_, const float* __restrict__ w1l_,
                     float* __restrict__ w0tm, float* __restrict__ w0tl,
                     float* __restrict__ w1tm, float* __restrict__ w1tl) {
    int t = blockIdx.x * 256 + threadIdx.x;      // t < 512*512
    int hp = t >> 9, h = t & 511;
    float mask = ((h % 255) >= (hp % 255)) ? 1.f : 0.f;  // dh_h >= dh_hp
    w1tm[t] = mask * w1m_[h * HH + hp];
    w1tl[t] = mask * w1l_[h * HH + hp];
    if (t < DD * HH) {
        int i = t >> 9, hh = t & 511;
        w0tm[t] = w0m_[hh * DD + i];
        w0tl[t] = w0l_[hh * DD + i];
    }
}

// ================= main: one wave per batch row, barrier-free K-loop ==========
struct Ctx {
    const float* x_s; const float* bom_s; const float* bol_s;
    const float* wom; const float* wol;
    const float* w0tm; const float* w0tl;
    const float* w1tm; const float* w1tl;
    float* out;
    int lane, row;
};

__device__ __forceinline__ void step_main(
    int i, const Ctx& c,
    float4 (&cWo)[4], float4 (&cW0)[4], float4 (&cW1a)[4], float4 (&cW1b)[4],
    float4 (&nWo)[4], float4 (&nW0)[4], float4 (&nW1a)[4], float4 (&nW1b)[4],
    float (&a0m)[8], float (&a0l)[8], float (&a1m)[8], float (&a1l)[8],
    float (&h1m)[8], float (&h1l)[8], float& ls_sum)
{
    // ---- prefetch step i+1 (clamped; no barriers => stays in flight) ----
    int ni = i + 1; if (ni > 255) ni = 255;
    int nb = ni + 255; if (nb > 511) nb = 511;
    loadr(nWo,  c.wom,  c.wol,  ni, c.lane);
    loadr(nW0,  c.w0tm, c.w0tl, ni, c.lane);
    loadr(nW1a, c.w1tm, c.w1tl, ni, c.lane);
    loadr(nW1b, c.w1tm, c.w1tl, nb, c.lane);

    // ---- output column i (mask mo implicit: h1 == 0 for un-finalized) ----
    float accm = dot8(cWo[0], cWo[1], h1m);
    float accl = dot8(cWo[2], cWo[3], h1l);
    #pragma unroll
    for (int o = 32; o > 0; o >>= 1) {
        accm += __shfl_xor(accm, o, 64);
        accl += __shfl_xor(accl, o, 64);
    }
    float mu = accm + c.bom_s[i];
    float ls = 0.5f * (accl + c.bol_s[i]);
    ls_sum += ls;
    float v = __fdividef(c.x_s[i] - mu, __expf(ls) + 1e-12f);
    if (c.lane == 0) c.out[c.row * DD + i] = v;

    // ---- a0 += v * W0[:,i] ----
    axpy8(a0m, cW0[0], cW0[1], v);
    axpy8(a0l, cW0[2], cW0[3], v);

    // ---- finalizers hp0=i, hp1=i+255 (callers guarantee i<255) ----
    int e0 = i & 3, l0 = i >> 2;
    float p0m = elu_f(bcast(sel8(a0m, e0), l0));
    float p0l = elu_f(bcast(sel8(a0l, e0), l0));
    int hp1 = i + 255;
    int e1 = 4 * (hp1 >> 8) + (hp1 & 3);
    int l1 = (hp1 & 255) >> 2;
    float p1m = elu_f(bcast(sel8(a0m, e1), l1));
    float p1l = elu_f(bcast(sel8(a0l, e1), l1));
    push2(a1m, cW1a[0], cW1a[1], cW1b[0], cW1b[1], p0m, p1m);
    push2(a1l, cW1a[2], cW1a[3], cW1b[2], cW1b[3], p0l, p1l);
}

__device__ __forceinline__ void step_fin(
    int i, const int (&fin)[8],
    float (&a1m)[8], float (&a1l)[8], float (&h1m)[8], float (&h1l)[8])
{
    #pragma unroll
    for (int e = 0; e < 8; ++e) {
        if (fin[e] == i) {
            h1m[e] = elu_f(a1m[e]);
            h1l[e] = elu_f(a1l[e]);
        }
    }
}

__global__ __launch_bounds__(64) void made_main(
    const float* __restrict__ x,
    const float* __restrict__ mu_b0, const float* __restrict__ mu_b1,
    const float* __restrict__ mu_bo,
    const float* __restrict__ lv_b0, const float* __restrict__ lv_b1,
    const float* __restrict__ lv_bo,
    const float* __restrict__ wom, const float* __restrict__ wol,
    const float* __restrict__ w0tm, const float* __restrict__ w0tl,
    const float* __restrict__ w1tm, const float* __restrict__ w1tl,
    float* __restrict__ out)
{
    __shared__ float4 x_s4[64], bom_s4[64], bol_s4[64];
    const int lane = threadIdx.x;
    const int row  = blockIdx.x;

    float a0m[8], a0l[8], a1m[8], a1l[8], h1m[8], h1l[8];
    int fin[8];
    {
        float4 t0, t1;
        t0 = ((const float4*)mu_b0)[lane]; t1 = ((const float4*)mu_b0)[64 + lane];
        a0m[0]=t0.x; a0m[1]=t0.y; a0m[2]=t0.z; a0m[3]=t0.w;
        a0m[4]=t1.x; a0m[5]=t1.y; a0m[6]=t1.z; a0m[7]=t1.w;
        t0 = ((const float4*)lv_b0)[lane]; t1 = ((const float4*)lv_b0)[64 + lane];
        a0l[0]=t0.x; a0l[1]=t0.y; a0l[2]=t0.z; a0l[3]=t0.w;
        a0l[4]=t1.x; a0l[5]=t1.y; a0l[6]=t1.z; a0l[7]=t1.w;
        t0 = ((const float4*)mu_b1)[lane]; t1 = ((const float4*)mu_b1)[64 + lane];
        a1m[0]=t0.x; a1m[1]=t0.y; a1m[2]=t0.z; a1m[3]=t0.w;
        a1m[4]=t1.x; a1m[5]=t1.y; a1m[6]=t1.z; a1m[7]=t1.w;
        t0 = ((const float4*)lv_b1)[lane]; t1 = ((const float4*)lv_b1)[64 + lane];
        a1l[0]=t0.x; a1l[1]=t0.y; a1l[2]=t0.z; a1l[3]=t0.w;
        a1l[4]=t1.x; a1l[5]=t1.y; a1l[6]=t1.z; a1l[7]=t1.w;
    }
    #pragma unroll
    for (int e = 0; e < 8; ++e) {
        h1m[e] = 0.f; h1l[e] = 0.f;
        int h = (e >> 2) * 256 + 4 * lane + (e & 3);
        fin[e] = h % 255;                      // finalize step = dh-1
    }
    x_s4[lane]   = ((const float4*)(x + row * DD))[lane];
    bom_s4[lane] = ((const float4*)mu_bo)[lane];
    bol_s4[lane] = ((const float4*)lv_bo)[lane];
    __syncthreads();

    Ctx c;
    c.x_s  = (const float*)x_s4;
    c.bom_s = (const float*)bom_s4;
    c.bol_s = (const float*)bol_s4;
    c.wom = wom; c.wol = wol;
    c.w0tm = w0tm; c.w0tl = w0tl;
    c.w1tm = w1tm; c.w1tl = w1tl;
    c.out = out; c.lane = lane; c.row = row;

    float ls_sum = 0.f;

    float4 AWo[4], AW0[4], AW1a[4], AW1b[4];
    float4 BWo[4], BW0[4], BW1a[4], BW1b[4];
    loadr(AWo,  wom,  wol,  0,   lane);
    loadr(AW0,  w0tm, w0tl, 0,   lane);
    loadr(AW1a, w1tm, w1tl, 0,   lane);
    loadr(AW1b, w1tm, w1tl, 255, lane);

    // ---- step 0 (extra finalizer h=510) ----
    step_main(0, c, AWo, AW0, AW1a, AW1b, BWo, BW0, BW1a, BW1b,
              a0m, a0l, a1m, a1l, h1m, h1l, ls_sum);
    {
        float4 E[4]; loadr(E, w1tm, w1tl, 510, lane);
        float pm = elu_f(bcast(sel8(a0m, 6), 63));
        float pl = elu_f(bcast(sel8(a0l, 6), 63));
        push1(a1m, E[0], E[1], pm);
        push1(a1l, E[2], E[3], pl);
    }
    step_fin(0, fin, a1m, a1l, h1m, h1l);

    // ---- step 1 (extra finalizer h=511) ----
    step_main(1, c, BWo, BW0, BW1a, BW1b, AWo, AW0, AW1a, AW1b,
              a0m, a0l, a1m, a1l, h1m, h1l, ls_sum);
    {
        float4 E[4]; loadr(E, w1tm, w1tl, 511, lane);
        float pm = elu_f(bcast(sel8(a0m, 7), 63));
        float pl = elu_f(bcast(sel8(a0l, 7), 63));
        push1(a1m, E[0], E[1], pm);
        push1(a1l, E[2], E[3], pl);
    }
    step_fin(1, fin, a1m, a1l, h1m, h1l);

    // ---- steps 2..253, ping-pong ----
    for (int i = 2; i < 254; i += 2) {
        step_main(i, c, AWo, AW0, AW1a, AW1b, BWo, BW0, BW1a, BW1b,
                  a0m, a0l, a1m, a1l, h1m, h1l, ls_sum);
        step_fin(i, fin, a1m, a1l, h1m, h1l);
        step_main(i + 1, c, BWo, BW0, BW1a, BW1b, AWo, AW0, AW1a, AW1b,
                  a0m, a0l, a1m, a1l, h1m, h1l, ls_sum);
        step_fin(i + 1, fin, a1m, a1l, h1m, h1l);
    }

    // ---- step 254 ----
    step_main(254, c, AWo, AW0, AW1a, AW1b, BWo, BW0, BW1a, BW1b,
              a0m, a0l, a1m, a1l, h1m, h1l, ls_sum);
    step_fin(254, fin, a1m, a1l, h1m, h1l);

    // ---- step 255: output only, no finalize ----
    {
        float accm = dot8(BWo[0], BWo[1], h1m);
        float accl = dot8(BWo[2], BWo[3], h1l);
        #pragma unroll
        for (int o = 32; o > 0; o >>= 1) {
            accm += __shfl_xor(accm, o, 64);
            accl += __shfl_xor(accl, o, 64);
        }
        float mu = accm + c.bom_s[255];
        float ls = 0.5f * (accl + c.bol_s[255]);
        ls_sum += ls;
        float v = __fdividef(c.x_s[255] - mu, __expf(ls) + 1e-12f);
        if (lane == 0) out[row * DD + 255] = v;
    }

    if (lane == 0) out[BB * DD + row] = ls_sum;
}

extern "C" void kernel_launch(void* const* d_in, const int* in_sizes, int n_in,
                              void* d_out, int out_size, void* d_ws, size_t ws_size,
                              hipStream_t stream) {
    const float* x     = (const float*)d_in[0];
    const float* mu_W0 = (const float*)d_in[1];
    const float* mu_b0 = (const float*)d_in[2];
    const float* mu_W1 = (const float*)d_in[3];
    const float* mu_b1 = (const float*)d_in[4];
    const float* mu_Wo = (const float*)d_in[5];
    const float* mu_bo = (const float*)d_in[6];
    const float* lv_W0 = (const float*)d_in[7];
    const float* lv_b0 = (const float*)d_in[8];
    const float* lv_W1 = (const float*)d_in[9];
    const float* lv_b1 = (const float*)d_in[10];
    const float* lv_Wo = (const float*)d_in[11];
    const float* lv_bo = (const float*)d_in[12];

    char* ws = (char*)d_ws;
    float* w0tm = (float*)(ws);                    // 256*512*4 = 512 KiB
    float* w0tl = (float*)(ws + 0x080000);         // 512 KiB
    float* w1tm = (float*)(ws + 0x100000);         // 1 MiB
    float* w1tl = (float*)(ws + 0x200000);         // 1 MiB  (total 3 MiB)

    prep<<<(HH * HH) / 256, 256, 0, stream>>>(mu_W0, lv_W0, mu_W1, lv_W1,
                                              w0tm, w0tl, w1tm, w1tl);
    made_main<<<BB, 64, 0, stream>>>(x, mu_b0, mu_b1, mu_bo,
                                     lv_b0, lv_b1, lv_bo,
                                     mu_Wo, lv_Wo, w0tm, w0tl, w1tm, w1tl,
                                     (float*)d_out);
}

// Round 5
// 288.261 us; speedup vs baseline: 2.1561x; 1.0991x over previous
//
#include <hip/hip_runtime.h>

#define DD 256
#define HH 512
#define BB 128

__device__ __forceinline__ float elu_f(float x) {
    return x > 0.f ? x : (__expf(x) - 1.f);
}

__device__ __forceinline__ float bcast(float v, int l) {
    return __uint_as_float(__builtin_amdgcn_readlane(__float_as_uint(v), (unsigned)l));
}

template <int CTRL, int RM>
__device__ __forceinline__ float dpp_add(float x) {
    int t = __builtin_amdgcn_update_dpp(0, __float_as_int(x), CTRL, RM, 0xf, true);
    return x + __int_as_float(t);
}

// full wave64 sum, result broadcast via lane 63 readlane (all-VALU, no LDS)
__device__ __forceinline__ float wave_reduce(float v) {
    v = dpp_add<0xB1, 0xf>(v);   // quad_perm [1,0,3,2]  : xor1
    v = dpp_add<0x4E, 0xf>(v);   // quad_perm [2,3,0,1]  : xor2
    v = dpp_add<0x141, 0xf>(v);  // row_half_mirror      : pair quads
    v = dpp_add<0x140, 0xf>(v);  // row_mirror           : pair 8-groups
    v = dpp_add<0x142, 0xa>(v);  // row_bcast15 -> rows 1,3
    v = dpp_add<0x143, 0xc>(v);  // row_bcast31 -> rows 2,3
    return bcast(v, 63);
}

__device__ __forceinline__ float sel8(const float (&a)[8], int e) {
    float v = a[0];
    #pragma unroll
    for (int k = 1; k < 8; ++k) v = (e == k) ? a[k] : v;
    return v;
}

__device__ __forceinline__ void loadr(float4 (&buf)[4], const float* pm, const float* pl,
                                      int r, int lane) {
    const float4* a = (const float4*)(pm + r * HH);
    const float4* b = (const float4*)(pl + r * HH);
    buf[0] = a[lane];
    buf[1] = a[64 + lane];
    buf[2] = b[lane];
    buf[3] = b[64 + lane];
}

__device__ __forceinline__ float dot8(const float4& w0, const float4& w1, const float (&h)[8]) {
    float p0 = w0.x*h[0] + w0.y*h[1];
    float p1 = w0.z*h[2] + w0.w*h[3];
    float p2 = w1.x*h[4] + w1.y*h[5];
    float p3 = w1.z*h[6] + w1.w*h[7];
    return (p0 + p1) + (p2 + p3);
}

__device__ __forceinline__ void axpy8(float (&a)[8], const float4& w0, const float4& w1, float v) {
    a[0] += v*w0.x; a[1] += v*w0.y; a[2] += v*w0.z; a[3] += v*w0.w;
    a[4] += v*w1.x; a[5] += v*w1.y; a[6] += v*w1.z; a[7] += v*w1.w;
}

__device__ __forceinline__ void push2(float (&a)[8], const float4& wA0, const float4& wA1,
                                      const float4& wB0, const float4& wB1, float p0, float p1) {
    a[0] += wA0.x*p0 + wB0.x*p1; a[1] += wA0.y*p0 + wB0.y*p1;
    a[2] += wA0.z*p0 + wB0.z*p1; a[3] += wA0.w*p0 + wB0.w*p1;
    a[4] += wA1.x*p0 + wB1.x*p1; a[5] += wA1.y*p0 + wB1.y*p1;
    a[6] += wA1.z*p0 + wB1.z*p1; a[7] += wA1.w*p0 + wB1.w*p1;
}

__device__ __forceinline__ void push1(float (&a)[8], const float4& w0, const float4& w1, float p) {
    a[0] += w0.x*p; a[1] += w0.y*p; a[2] += w0.z*p; a[3] += w0.w*p;
    a[4] += w1.x*p; a[5] += w1.y*p; a[6] += w1.z*p; a[7] += w1.w*p;
}

// ---- prep: LDS-tiled transpose, coalesced read AND write.
// blocks 0..255: W1 (512x512, masked). blocks 256..383: W0 (512x256, unmasked).
// dst[c*512 + r] = mask(r,c) * src[r*C + c]
__global__ __launch_bounds__(256) void prep_t(
    const float* __restrict__ w0m_, const float* __restrict__ w0l_,
    const float* __restrict__ w1m_, const float* __restrict__ w1l_,
    float* __restrict__ w0tm, float* __restrict__ w0tl,
    float* __restrict__ w1tm, float* __restrict__ w1tl)
{
    __shared__ float tm[32][33], tl[32][33];
    const int tx = threadIdx.x & 31, ty = threadIdx.x >> 5;
    const bool isW1 = blockIdx.x < 256;
    const int bid = isW1 ? blockIdx.x : blockIdx.x - 256;
    const float* sm = isW1 ? w1m_ : w0m_;
    const float* sl = isW1 ? w1l_ : w0l_;
    float* dm = isW1 ? w1tm : w0tm;
    float* dl = isW1 ? w1tl : w0tl;
    const int C = isW1 ? 512 : 256;
    const int shiftC = isW1 ? 4 : 3;            // tiles along C
    const int bx = bid & ((1 << shiftC) - 1), by = bid >> shiftC;
    const int c0 = bx << 5, r0 = by << 5;

    #pragma unroll
    for (int j = 0; j < 4; ++j) {
        int r = r0 + ty + 8 * j;
        tm[ty + 8 * j][tx] = sm[r * C + c0 + tx];
        tl[ty + 8 * j][tx] = sl[r * C + c0 + tx];
    }
    __syncthreads();
    #pragma unroll
    for (int j = 0; j < 4; ++j) {
        int c = c0 + ty + 8 * j;
        int r = r0 + tx;
        float mask = 1.f;
        if (isW1) mask = ((r % 255) >= (c % 255)) ? 1.f : 0.f;   // dh_h >= dh_hp
        dm[c * HH + r] = mask * tm[tx][ty + 8 * j];
        dl[c * HH + r] = mask * tl[tx][ty + 8 * j];
    }
}

// ================= main: one wave per batch row =================
struct Ctx {
    const float* x_s; const float* bom_s; const float* bol_s;
    const float* wom; const float* wol;
    const float* w0tm; const float* w0tl;
    const float* w1tm; const float* w1tl;
    float* out;
    int lane, row;
};

struct WSet { float4 Wo[4]; float4 W0[4]; float4 W1a[4]; float4 W1b[4]; };

__device__ __forceinline__ void load_set(WSet& S, const Ctx& c, int i) {
    int ni = i > 255 ? 255 : i;
    int nb = ni + 255; if (nb > 510) nb = 510;
    loadr(S.Wo,  c.wom,  c.wol,  ni, c.lane);
    loadr(S.W0,  c.w0tm, c.w0tl, ni, c.lane);
    loadr(S.W1a, c.w1tm, c.w1tl, ni, c.lane);
    loadr(S.W1b, c.w1tm, c.w1tl, nb, c.lane);
}

__device__ __forceinline__ void step_main(
    int i, const Ctx& c, WSet& cur, WSet& pf,
    float (&a0m)[8], float (&a0l)[8], float (&a1m)[8], float (&a1l)[8],
    float (&h1m)[8], float (&h1l)[8], float& ls_sum)
{
    // distance-2 prefetch into the set freed at step i-1
    load_set(pf, c, i + 2);

    // output column i (mask mo implicit: h1 == 0 for un-finalized units)
    float accm = wave_reduce(dot8(cur.Wo[0], cur.Wo[1], h1m));
    float accl = wave_reduce(dot8(cur.Wo[2], cur.Wo[3], h1l));
    float mu = accm + c.bom_s[i];
    float ls = 0.5f * (accl + c.bol_s[i]);
    ls_sum += ls;
    float v = __fdividef(c.x_s[i] - mu, __expf(ls) + 1e-12f);
    if (c.lane == 0) c.out[c.row * DD + i] = v;

    // a0 += v * W0[:,i]
    axpy8(a0m, cur.W0[0], cur.W0[1], v);
    axpy8(a0l, cur.W0[2], cur.W0[3], v);

    // finalizers hp0 = i, hp1 = i+255  (i < 255 guaranteed by callers)
    int e0 = i & 3, l0 = i >> 2;
    float p0m = elu_f(bcast(sel8(a0m, e0), l0));
    float p0l = elu_f(bcast(sel8(a0l, e0), l0));
    int hp1 = i + 255;
    int e1 = 4 * (hp1 >> 8) + (hp1 & 3);
    int l1 = (hp1 & 255) >> 2;
    float p1m = elu_f(bcast(sel8(a0m, e1), l1));
    float p1l = elu_f(bcast(sel8(a0l, e1), l1));
    push2(a1m, cur.W1a[0], cur.W1a[1], cur.W1b[0], cur.W1b[1], p0m, p1m);
    push2(a1l, cur.W1a[2], cur.W1a[3], cur.W1b[2], cur.W1b[3], p0l, p1l);
}

__device__ __forceinline__ void step_fin(
    int i, const int (&fin)[8],
    float (&a1m)[8], float (&a1l)[8], float (&h1m)[8], float (&h1l)[8])
{
    #pragma unroll
    for (int e = 0; e < 8; ++e) {
        if (fin[e] == i) {
            h1m[e] = elu_f(a1m[e]);
            h1l[e] = elu_f(a1l[e]);
        }
    }
}

__global__ __launch_bounds__(64, 1) void made_main(
    const float* __restrict__ x,
    const float* __restrict__ mu_b0, const float* __restrict__ mu_b1,
    const float* __restrict__ mu_bo,
    const float* __restrict__ lv_b0, const float* __restrict__ lv_b1,
    const float* __restrict__ lv_bo,
    const float* __restrict__ wom, const float* __restrict__ wol,
    const float* __restrict__ w0tm, const float* __restrict__ w0tl,
    const float* __restrict__ w1tm, const float* __restrict__ w1tl,
    float* __restrict__ out)
{
    __shared__ float4 x_s4[64], bom_s4[64], bol_s4[64];
    const int lane = threadIdx.x;
    const int row  = blockIdx.x;

    float a0m[8], a0l[8], a1m[8], a1l[8], h1m[8], h1l[8];
    int fin[8];
    {
        float4 t0, t1;
        t0 = ((const float4*)mu_b0)[lane]; t1 = ((const float4*)mu_b0)[64 + lane];
        a0m[0]=t0.x; a0m[1]=t0.y; a0m[2]=t0.z; a0m[3]=t0.w;
        a0m[4]=t1.x; a0m[5]=t1.y; a0m[6]=t1.z; a0m[7]=t1.w;
        t0 = ((const float4*)lv_b0)[lane]; t1 = ((const float4*)lv_b0)[64 + lane];
        a0l[0]=t0.x; a0l[1]=t0.y; a0l[2]=t0.z; a0l[3]=t0.w;
        a0l[4]=t1.x; a0l[5]=t1.y; a0l[6]=t1.z; a0l[7]=t1.w;
        t0 = ((const float4*)mu_b1)[lane]; t1 = ((const float4*)mu_b1)[64 + lane];
        a1m[0]=t0.x; a1m[1]=t0.y; a1m[2]=t0.z; a1m[3]=t0.w;
        a1m[4]=t1.x; a1m[5]=t1.y; a1m[6]=t1.z; a1m[7]=t1.w;
        t0 = ((const float4*)lv_b1)[lane]; t1 = ((const float4*)lv_b1)[64 + lane];
        a1l[0]=t0.x; a1l[1]=t0.y; a1l[2]=t0.z; a1l[3]=t0.w;
        a1l[4]=t1.x; a1l[5]=t1.y; a1l[6]=t1.z; a1l[7]=t1.w;
    }
    #pragma unroll
    for (int e = 0; e < 8; ++e) {
        h1m[e] = 0.f; h1l[e] = 0.f;
        int h = (e >> 2) * 256 + 4 * lane + (e & 3);
        fin[e] = h % 255;
    }
    x_s4[lane]   = ((const float4*)(x + row * DD))[lane];
    bom_s4[lane] = ((const float4*)mu_bo)[lane];
    bol_s4[lane] = ((const float4*)lv_bo)[lane];
    __syncthreads();

    Ctx c;
    c.x_s  = (const float*)x_s4;
    c.bom_s = (const float*)bom_s4;
    c.bol_s = (const float*)bol_s4;
    c.wom = wom; c.wol = wol;
    c.w0tm = w0tm; c.w0tl = w0tl;
    c.w1tm = w1tm; c.w1tl = w1tl;
    c.out = out; c.lane = lane; c.row = row;

    float ls_sum = 0.f;

    WSet S0, S1, S2;
    float4 E0[4], E1[4];
    load_set(S0, c, 0);
    load_set(S1, c, 1);
    loadr(E0, w1tm, w1tl, 510, lane);
    loadr(E1, w1tm, w1tl, 511, lane);

    // ---- step 0 (extra finalizer h=510) ----
    step_main(0, c, S0, S2, a0m, a0l, a1m, a1l, h1m, h1l, ls_sum);
    {
        float pm = elu_f(bcast(sel8(a0m, 6), 63));
        float pl = elu_f(bcast(sel8(a0l, 6), 63));
        push1(a1m, E0[0], E0[1], pm);
        push1(a1l, E0[2], E0[3], pl);
    }
    step_fin(0, fin, a1m, a1l, h1m, h1l);

    // ---- step 1 (extra finalizer h=511) ----
    step_main(1, c, S1, S0, a0m, a0l, a1m, a1l, h1m, h1l, ls_sum);
    {
        float pm = elu_f(bcast(sel8(a0m, 7), 63));
        float pl = elu_f(bcast(sel8(a0l, 7), 63));
        push1(a1m, E1[0], E1[1], pm);
        push1(a1l, E1[2], E1[3], pl);
    }
    step_fin(1, fin, a1m, a1l, h1m, h1l);

    // ---- steps 2..253, 3-set rotation (84 trios) ----
    #pragma unroll 1
    for (int i = 2; i < 254; i += 3) {
        step_main(i,     c, S2, S1, a0m, a0l, a1m, a1l, h1m, h1l, ls_sum);
        step_fin(i, fin, a1m, a1l, h1m, h1l);
        step_main(i + 1, c, S0, S2, a0m, a0l, a1m, a1l, h1m, h1l, ls_sum);
        step_fin(i + 1, fin, a1m, a1l, h1m, h1l);
        step_main(i + 2, c, S1, S0, a0m, a0l, a1m, a1l, h1m, h1l, ls_sum);
        step_fin(i + 2, fin, a1m, a1l, h1m, h1l);
    }

    // ---- step 254 (cur = S2, prefetch harmless) ----
    step_main(254, c, S2, S1, a0m, a0l, a1m, a1l, h1m, h1l, ls_sum);
    step_fin(254, fin, a1m, a1l, h1m, h1l);

    // ---- step 255: output only (cur = S0) ----
    {
        float accm = wave_reduce(dot8(S0.Wo[0], S0.Wo[1], h1m));
        float accl = wave_reduce(dot8(S0.Wo[2], S0.Wo[3], h1l));
        float mu = accm + c.bom_s[255];
        float ls = 0.5f * (accl + c.bol_s[255]);
        ls_sum += ls;
        float v = __fdividef(c.x_s[255] - mu, __expf(ls) + 1e-12f);
        if (lane == 0) out[row * DD + 255] = v;
    }

    if (lane == 0) out[BB * DD + row] = ls_sum;
}

extern "C" void kernel_launch(void* const* d_in, const int* in_sizes, int n_in,
                              void* d_out, int out_size, void* d_ws, size_t ws_size,
                              hipStream_t stream) {
    const float* x     = (const float*)d_in[0];
    const float* mu_W0 = (const float*)d_in[1];
    const float* mu_b0 = (const float*)d_in[2];
    const float* mu_W1 = (const float*)d_in[3];
    const float* mu_b1 = (const float*)d_in[4];
    const float* mu_Wo = (const float*)d_in[5];
    const float* mu_bo = (const float*)d_in[6];
    const float* lv_W0 = (const float*)d_in[7];
    const float* lv_b0 = (const float*)d_in[8];
    const float* lv_W1 = (const float*)d_in[9];
    const float* lv_b1 = (const float*)d_in[10];
    const float* lv_Wo = (const float*)d_in[11];
    const float* lv_bo = (const float*)d_in[12];

    char* ws = (char*)d_ws;
    float* w0tm = (float*)(ws);                    // 512 KiB
    float* w0tl = (float*)(ws + 0x080000);         // 512 KiB
    float* w1tm = (float*)(ws + 0x100000);         // 1 MiB
    float* w1tl = (float*)(ws + 0x200000);         // 1 MiB

    prep_t<<<384, 256, 0, stream>>>(mu_W0, lv_W0, mu_W1, lv_W1,
                                    w0tm, w0tl, w1tm, w1tl);
    made_main<<<BB, 64, 0, stream>>>(x, mu_b0, mu_b1, mu_bo,
                                     lv_b0, lv_b1, lv_bo,
                                     mu_Wo, lv_Wo, w0tm, w0tl, w1tm, w1tl,
                                     (float*)d_out);
}